// Round 1
// baseline (263.248 us; speedup 1.0000x reference)
//
#include <hip/hip_runtime.h>

// Patch-embedding rearrange: (B=256, C=3, H=224, W=224) fp32
//   -> (B, 196, 768) where out[b][ph*14+pw][c*256+i*16+j] = in[b][c][ph*16+i][pw*16+j]
// Pure permute, memory-bound. Strategy: output-coalesced float4 gather.
// All float4 accesses are 16B-aligned (strides 224/50176/150528 are %4==0).

constexpr int B  = 256;
constexpr int C  = 3;
constexpr int H  = 224;
constexpr int W  = 224;
constexpr int P  = 16;
constexpr int PW_ = W / P;          // 14
constexpr int NP = (H / P) * PW_;   // 196 patches
constexpr int E  = C * P * P;       // 768 embed dim
constexpr int E4 = E / 4;           // 192 float4 per output row
constexpr long long TOTAL4 = (long long)B * NP * E4;  // 9,633,792 float4s

__global__ __launch_bounds__(256)
void patch_rearrange_kernel(const float4* __restrict__ in, float4* __restrict__ out) {
    int t = blockIdx.x * blockDim.x + threadIdx.x;
    // t indexes output float4s in row-major output order (write-coalesced).
    int e4   = t % E4;          // 0..191  (= c*64 + i*4 + j/4)
    int rest = t / E4;
    int p    = rest % NP;       // 0..195
    int b    = rest / NP;

    int c  = e4 >> 6;           // /64
    int i  = (e4 & 63) >> 2;    // row inside patch, 0..15
    int j4 = e4 & 3;            // float4 column inside patch, 0..3
    int ph = p / PW_;
    int pw = p - ph * PW_;

    // input float4 index: ((b*C + c)*H + (ph*16 + i)) * (W/4) + pw*4 + j4
    int in_idx = ((b * C + c) * H + (ph * P + i)) * (W / 4) + pw * (P / 4) + j4;
    out[t] = in[in_idx];
}

extern "C" void kernel_launch(void* const* d_in, const int* in_sizes, int n_in,
                              void* d_out, int out_size, void* d_ws, size_t ws_size,
                              hipStream_t stream) {
    const float4* in  = (const float4*)d_in[0];
    float4*       out = (float4*)d_out;
    // TOTAL4 = 9,633,792 = 37,632 blocks * 256 threads exactly (no tail).
    int blocks = (int)(TOTAL4 / 256);
    patch_rearrange_kernel<<<blocks, 256, 0, stream>>>(in, out);
}